// Round 1
// baseline (1794.081 us; speedup 1.0000x reference)
//
#include <hip/hip_runtime.h>
#include <hip/hip_bf16.h>
#include <stdint.h>
#include <math.h>

#define B   64
#define T   1000
#define INP 64
#define HID 512
#define ACT 2

#define NSLICE 4                    // column slices per row-group
#define MROWS  2                    // batch rows per block
#define NGROUP (B / MROWS)          // 32 row-groups
#define NBLOCKS (NGROUP * NSLICE)   // 128 blocks — co-resident at 1 blk/CU
#define COLS   (HID / NSLICE)       // 128 cols per block
#define HLPAD  544                  // row stride (shorts): bank shift 16/row

#define FAST_GUARD 1024             // fast-poll timeout (one-shot per wave)

typedef __attribute__((ext_vector_type(8))) short short8;   // 8 bf16
typedef __attribute__((ext_vector_type(4))) float floatx4;  // MFMA C/D

// ---------------------------------------------------------------------------
// L2 fast-path primitives. The 4 blocks of a row-group are blockIdx ≡ g
// (mod 8) -> same XCD under round-robin dispatch -> shared L2.
//   load : sc0 = bypass L1, read the XCD's L2 (fresh data from peer CUs)
//   store: plain (no sc bits) = write-through L1 into own-XCD L2
// Correctness does NOT depend on this mapping: tag-checked fallback below.
// ---------------------------------------------------------------------------
__device__ __forceinline__ uint64_t l2_load64(const uint64_t* p) {
  uint64_t v;
  asm volatile("global_load_dwordx2 %0, %1, off sc0\n\t"
               "s_waitcnt vmcnt(0)"
               : "=v"(v) : "v"(p) : "memory");
  return v;
}
__device__ __forceinline__ void l2_store64(uint64_t* p, uint64_t v) {
  asm volatile("global_store_dwordx2 %0, %1, off"
               :: "v"(p), "v"(v) : "memory");
}

// ---------------------------------------------------------------------------
// Exchange word layout: [parity][group][col] -> u64 = (row1 << 32) | row0,
// each u32 = (bf16 bits << 16) | (step_tag & 0xFFFF); h_t carries tag t+1.
// K0: init — hn (fp32) -> tagged words, parity-1, tag 0 (=h_{-1}); poison p0.
// ---------------------------------------------------------------------------
__global__ __launch_bounds__(256) void init_kernel(
    const float* __restrict__ hn, uint64_t* __restrict__ h_fast,
    uint64_t* __restrict__ h_safe) {
  const int i   = blockIdx.x * 256 + threadIdx.x;  // 0 .. NGROUP*HID-1
  const int g   = i >> 9;                          // / HID
  const int col = i & (HID - 1);
  __hip_bfloat16 b0 = __float2bfloat16(hn[(2 * g) * HID + col]);
  __hip_bfloat16 b1 = __float2bfloat16(hn[(2 * g + 1) * HID + col]);
  const uint32_t w0 = ((uint32_t)*reinterpret_cast<unsigned short*>(&b0)) << 16;
  const uint32_t w1 = ((uint32_t)*reinterpret_cast<unsigned short*>(&b1)) << 16;
  const uint64_t v  = (uint64_t)w0 | ((uint64_t)w1 << 32);  // tag 0
  const size_t p1 = (size_t)NGROUP * HID + i;               // parity 1
  h_fast[p1] = v;
  h_safe[p1] = v;
  h_fast[i] = 0x0000FFFE0000FFFEull;  // parity 0: non-matching tag
  h_safe[i] = 0x0000FFFE0000FFFEull;
}

// ---------------------------------------------------------------------------
// K1: xproj[b,t,:] = inp[b,t,:] @ W_ih  -> rnn slab (overwritten by h later)
// ---------------------------------------------------------------------------
__global__ __launch_bounds__(256) void xproj_kernel(
    const float* __restrict__ inp, const float* __restrict__ W_ih,
    float* __restrict__ rnn) {
  __shared__ float xin[16 * INP];
  const int tid = threadIdx.x;
  const long r0 = (long)blockIdx.x * 16;

  const float4* inp4 = (const float4*)(inp + r0 * INP);
  ((float4*)xin)[tid] = inp4[tid];
  __syncthreads();

  const int j = tid, j2 = tid + 256;
  float acc0[16], acc1[16];
#pragma unroll
  for (int r = 0; r < 16; ++r) { acc0[r] = 0.f; acc1[r] = 0.f; }

  for (int i = 0; i < INP; ++i) {
    const float w0 = W_ih[i * HID + j];
    const float w1 = W_ih[i * HID + j2];
#pragma unroll
    for (int r = 0; r < 16; ++r) {
      const float x = xin[r * INP + i];
      acc0[r] = fmaf(x, w0, acc0[r]);
      acc1[r] = fmaf(x, w1, acc1[r]);
    }
  }
#pragma unroll
  for (int r = 0; r < 16; ++r) {
    rnn[(r0 + r) * HID + j]  = acc0[r];
    rnn[(r0 + r) * HID + j2] = acc1[r];
  }
}

// ---------------------------------------------------------------------------
// K2: recurrence. W_hh register-resident bf16 B-frags. Fence-free tagged-word
// exchange: same-XCD L2 fast path (plain store + sc0 poll) with sticky
// agent-scope LLC fallback; own-slice cols bypass via direct LDS writes.
// ---------------------------------------------------------------------------
__global__ __launch_bounds__(512) void rnn_mfma(
    const float* __restrict__ W_hh, float* __restrict__ rnn,
    float* __restrict__ hn_out, uint64_t* __restrict__ h_fast,
    uint64_t* __restrict__ h_safe) {
  // [parity][row][col] with row stride 544 shorts (1088 B -> bank shift 16):
  // the 8 distinct b128 read addresses per wave hit 8 distinct bank-quads.
  __shared__ __align__(16) unsigned short hl[2][MROWS][HLPAD];

  const int tid  = threadIdx.x;
  const int lane = tid & 63;
  const int w    = tid >> 6;              // wave 0..7
  const int g    = blockIdx.x & (NGROUP - 1);
  const int s    = blockIdx.x >> 5;       // col-slice 0..3
  const int r0   = g * MROWS;
  const int n_base = s * COLS + w * 16;

  const int lm = lane & 15;               // MFMA m/n lane index
  const int lq = lane >> 4;               // quad 0..3 -> k-subchunk
  const int cc = n_base + lm;             // this lane's output column

  // ---- one-time: W_hh column slice -> bf16 B-frags
  // lane holds B[k = kt*32 + lq*8 + i][n = lm]
  short8 bfrag[16];
#pragma unroll
  for (int kt = 0; kt < 16; ++kt) {
    short8 f;
#pragma unroll
    for (int i = 0; i < 8; ++i) {
      const int k = kt * 32 + lq * 8 + i;
      __hip_bfloat16 hb = __float2bfloat16(W_hh[k * HID + cc]);
      f[i] = *reinterpret_cast<short*>(&hb);
    }
    bfrag[kt] = f;
  }

  const int  arow   = lm & 1;             // A row duplication (M=2 real rows)
  const bool remote = ((tid >> 7) != s);  // wave-uniform: outside own slice?
  const bool prod   = (lq == 0);          // producer lanes (hold C rows 0,1)

  // xp double-buffer: producer lanes only
  long ro0 = ((long)r0 * T + 0) * HID + cc;
  long ro1 = ((long)(r0 + 1) * T + 0) * HID + cc;
  float xp0 = 0.f, xp1 = 0.f;
  if (prod) { xp0 = rnn[ro0]; xp1 = rnn[ro1]; }

  int fastmode = 1;                       // sticky: drops to 0 on timeout

  for (int t = 0; t < T; ++t) {
    const int p = (t + 1) & 1;            // parity holding h_{t-1}

    // ---- poll tagged words (remote cols; everything at t==0)
    if (t == 0 || remote) {
      const size_t idx = ((size_t)p * NGROUP + g) * HID + tid;
      const uint64_t want = (uint64_t)(t & 0xFFFF) * 0x0000000100000001ull;
      uint64_t v = 0;
      if (fastmode) {
        int ok = 0;
        for (int it = 0; it < FAST_GUARD; ++it) {
          v = l2_load64(h_fast + idx);
          if (((v ^ want) & 0x0000FFFF0000FFFFull) == 0) { ok = 1; break; }
        }
        if (!ok) fastmode = 0;            // peer not L2-visible: cross-XCD
      }
      if (!fastmode) {                    // guaranteed path via LLC
        int guard = 0;
        for (;;) {
          v = __hip_atomic_load(h_safe + idx, __ATOMIC_RELAXED,
                                __HIP_MEMORY_SCOPE_AGENT);
          if (((v ^ want) & 0x0000FFFF0000FFFFull) == 0) break;
          if (++guard > (1 << 20)) break; // never hang the harness
        }
      }
      hl[p][0][tid] = (unsigned short)((uint32_t)v >> 16);
      hl[p][1][tid] = (unsigned short)((uint32_t)(v >> 32) >> 16);
    }
    __syncthreads();                      // one barrier/step (parity dbuf)

    // prefetch next step's xproj (hidden under MFMA + next poll)
    float nxp0 = 0.f, nxp1 = 0.f;
    long nro0 = ro0, nro1 = ro1;
    if (prod && t + 1 < T) {
      nro0 = ro0 + HID; nro1 = ro1 + HID;
      nxp0 = rnn[nro0]; nxp1 = rnn[nro1];
    }

    // ---- 16 MFMA over k, 4 independent chains (depth 4)
    floatx4 c0 = {0.f, 0.f, 0.f, 0.f}, c1 = c0, c2 = c0, c3 = c0;
    const unsigned short* ap = &hl[p][arow][lq * 8];
#pragma unroll
    for (int kt = 0; kt < 16; kt += 4) {
      short8 a0 = *(const short8*)(ap + (kt + 0) * 32);
      short8 a1 = *(const short8*)(ap + (kt + 1) * 32);
      short8 a2 = *(const short8*)(ap + (kt + 2) * 32);
      short8 a3 = *(const short8*)(ap + (kt + 3) * 32);
      c0 = __builtin_amdgcn_mfma_f32_16x16x32_bf16(a0, bfrag[kt + 0], c0, 0, 0, 0);
      c1 = __builtin_amdgcn_mfma_f32_16x16x32_bf16(a1, bfrag[kt + 1], c1, 0, 0, 0);
      c2 = __builtin_amdgcn_mfma_f32_16x16x32_bf16(a2, bfrag[kt + 2], c2, 0, 0, 0);
      c3 = __builtin_amdgcn_mfma_f32_16x16x32_bf16(a3, bfrag[kt + 3], c3, 0, 0, 0);
    }

    if (prod) {  // C layout: col = lane&15, row = (lane>>4)*4 + reg
      const float z0 = c0[0] + c1[0] + c2[0] + c3[0] + xp0;
      const float z1 = c0[1] + c1[1] + c2[1] + c3[1] + xp1;
      const float h0 = 1.f / (1.f + __expf(-z0));
      const float h1 = 1.f / (1.f + __expf(-z1));
      __hip_bfloat16 b0 = __float2bfloat16(h0);
      __hip_bfloat16 b1 = __float2bfloat16(h1);
      const unsigned short u0 = *reinterpret_cast<unsigned short*>(&b0);
      const unsigned short u1 = *reinterpret_cast<unsigned short*>(&b1);

      // critical path first: tagged word for remote consumers
      const uint32_t tag = (uint32_t)(t + 1) & 0xFFFFu;
      const uint64_t word =
          (uint64_t)(((uint32_t)u0 << 16) | tag) |
          ((uint64_t)(((uint32_t)u1 << 16) | tag) << 32);
      const size_t didx = ((size_t)(t & 1) * NGROUP + g) * HID + cc;
      l2_store64(h_fast + didx, word);    // same-XCD L2 (fast consumers)
      __hip_atomic_store(h_safe + didx, word, __ATOMIC_RELAXED,
                         __HIP_MEMORY_SCOPE_AGENT);  // LLC (fallback path)

      // own-slice bypass: stage h_t for our own next step directly in LDS
      hl[t & 1][0][cc] = u0;
      hl[t & 1][1][cc] = u1;

      // non-critical: f32 outputs
      rnn[ro0] = h0;
      rnn[ro1] = h1;
      if (t == T - 1) {
        hn_out[r0 * HID + cc]       = h0;
        hn_out[(r0 + 1) * HID + cc] = h1;
      }
      xp0 = nxp0; xp1 = nxp1; ro0 = nro0; ro1 = nro1;
    }
  }
}

// ---------------------------------------------------------------------------
// K3: out[b,t,:] = sigmoid(rnn[b,t,:] @ W_fc + b_fc)
// ---------------------------------------------------------------------------
__global__ __launch_bounds__(256) void fc_kernel(
    const float* __restrict__ rnn, const float* __restrict__ W_fc,
    const float* __restrict__ b_fc, float* __restrict__ out) {
  const int lane = threadIdx.x & 63;
  const int wid  = threadIdx.x >> 6;
  const long row = (long)blockIdx.x * 4 + wid;

  const float4* __restrict__ hrow = (const float4*)(rnn + row * HID);
  const float4* __restrict__ Wfc4 = (const float4*)W_fc;

  float a0 = 0.f, a1 = 0.f;
#pragma unroll
  for (int u = 0; u < 2; ++u) {
    const float4 hv = hrow[lane * 2 + u];
    const int j0 = lane * 8 + u * 4;
    const float4 wA = Wfc4[(j0 >> 1)];
    const float4 wB = Wfc4[(j0 >> 1) + 1];
    a0 += hv.x * wA.x + hv.y * wA.z + hv.z * wB.x + hv.w * wB.z;
    a1 += hv.x * wA.y + hv.y * wA.w + hv.z * wB.y + hv.w * wB.w;
  }
#pragma unroll
  for (int off = 32; off > 0; off >>= 1) {
    a0 += __shfl_down(a0, off, 64);
    a1 += __shfl_down(a1, off, 64);
  }
  if (lane == 0) {
    out[row * 2 + 0] = 1.f / (1.f + __expf(-(a0 + b_fc[0])));
    out[row * 2 + 1] = 1.f / (1.f + __expf(-(a1 + b_fc[1])));
  }
}

// ---------------------------------------------------------------------------
extern "C" void kernel_launch(void* const* d_in, const int* in_sizes, int n_in,
                              void* d_out, int out_size, void* d_ws,
                              size_t ws_size, hipStream_t stream) {
  const float* inp  = (const float*)d_in[0];
  const float* hn   = (const float*)d_in[1];
  const float* W_hh = (const float*)d_in[2];
  const float* W_ih = (const float*)d_in[3];
  const float* W_fc = (const float*)d_in[4];
  const float* b_fc = (const float*)d_in[5];

  float* out    = (float*)d_out;              // [B,T,ACT]
  float* hn_out = out + (long)B * T * ACT;    // [1,B,HID]
  float* rnn    = hn_out + (long)B * HID;     // [B,T,HID]

  // workspace: h_fast[2][NGROUP][HID] + h_safe[...] u64 words (256 KB each)
  uint64_t* h_fast = (uint64_t*)d_ws;
  const size_t HCNT = (size_t)2 * NGROUP * HID;
  uint64_t* h_safe =
      (ws_size >= 2 * HCNT * sizeof(uint64_t)) ? (h_fast + HCNT) : h_fast;

  hipLaunchKernelGGL(init_kernel, dim3((NGROUP * HID) / 256), dim3(256), 0,
                     stream, hn, h_fast, h_safe);
  hipLaunchKernelGGL(xproj_kernel, dim3((B * T) / 16), dim3(256), 0, stream,
                     inp, W_ih, rnn);
  hipLaunchKernelGGL(rnn_mfma, dim3(NBLOCKS), dim3(512), 0, stream,
                     W_hh, rnn, hn_out, h_fast, h_safe);
  hipLaunchKernelGGL(fc_kernel, dim3((B * T) / 4), dim3(256), 0, stream,
                     rnn, W_fc, b_fc, out);
}

// Round 2
// 1497.019 us; speedup vs baseline: 1.1984x; 1.1984x over previous
//
#include <hip/hip_runtime.h>
#include <hip/hip_bf16.h>
#include <stdint.h>
#include <math.h>

#define B   64
#define T   1000
#define INP 64
#define HID 512
#define ACT 2

#define NSLICE 4                    // column slices per row-group
#define MROWS  2                    // batch rows per block
#define NGROUP (B / MROWS)          // 32 row-groups
#define NBLOCKS (NGROUP * NSLICE)   // 128 worker slots
#define NLAUNCH 256                 // launched blocks (claim surplus)
#define WORK_PER_XCD 16             // 4 groups x 4 slices per XCD
#define COLS   (HID / NSLICE)       // 128 cols per block
#define HLPAD  544                  // row stride (shorts): bank shift 16/row

#define FAST_GUARD 256              // fast-poll timeout (sticky, one-shot)

typedef __attribute__((ext_vector_type(8))) short short8;   // 8 bf16
typedef __attribute__((ext_vector_type(4))) float floatx4;  // MFMA C/D

// ---------------------------------------------------------------------------
// L2 fast-path primitives (same-XCD L2 is shared by all CUs on the XCD):
//   load : sc0 = bypass L1, read the XCD's L2 (fresh data from peer CUs)
//   store: plain = write-through L1 into own-XCD L2
// Same-XCD grouping is GUARANTEED by the claim protocol below (HW_REG_XCC_ID),
// and a tag-checked sticky fallback covers any residual visibility failure.
// ---------------------------------------------------------------------------
__device__ __forceinline__ uint64_t l2_load64(const uint64_t* p) {
  uint64_t v;
  asm volatile("global_load_dwordx2 %0, %1, off sc0\n\t"
               "s_waitcnt vmcnt(0)"
               : "=v"(v) : "v"(p) : "memory");
  return v;
}
__device__ __forceinline__ void l2_store64(uint64_t* p, uint64_t v) {
  asm volatile("global_store_dwordx2 %0, %1, off"
               :: "v"(p), "v"(v) : "memory");
}
__device__ __forceinline__ int get_xcc_id() {
  int x;
  asm volatile("s_getreg_b32 %0, hwreg(HW_REG_XCC_ID)" : "=s"(x));
  return x & 7;
}

// ctrl layout (u32): [0..7] per-XCD claim counters, [8] claimed, [9] arrivals,
// [10] mode flag (0=undecided, 1=fallback layout, 2=XCD layout)
#define CTRL_WORDS 16

// ---------------------------------------------------------------------------
// Exchange word layout: [parity][group][col] -> u64 = (row1 << 32) | row0,
// each u32 = (bf16 bits << 16) | (step_tag & 0xFFFF); h_t carries tag t+1.
// K0: init — hn -> tagged words, parity-1, tag 0 (=h_{-1}); poison parity-0;
// zero the ctrl block.
// ---------------------------------------------------------------------------
__global__ __launch_bounds__(256) void init_kernel(
    const float* __restrict__ hn, uint64_t* __restrict__ h_fast,
    uint64_t* __restrict__ h_safe, uint32_t* __restrict__ ctrl) {
  if (blockIdx.x == 0 && threadIdx.x < CTRL_WORDS) ctrl[threadIdx.x] = 0;
  const int i   = blockIdx.x * 256 + threadIdx.x;  // 0 .. NGROUP*HID-1
  const int g   = i >> 9;                          // / HID
  const int col = i & (HID - 1);
  __hip_bfloat16 b0 = __float2bfloat16(hn[(2 * g) * HID + col]);
  __hip_bfloat16 b1 = __float2bfloat16(hn[(2 * g + 1) * HID + col]);
  const uint32_t w0 = ((uint32_t)*reinterpret_cast<unsigned short*>(&b0)) << 16;
  const uint32_t w1 = ((uint32_t)*reinterpret_cast<unsigned short*>(&b1)) << 16;
  const uint64_t v  = (uint64_t)w0 | ((uint64_t)w1 << 32);  // tag 0
  const size_t p1 = (size_t)NGROUP * HID + i;               // parity 1
  h_fast[p1] = v;
  h_safe[p1] = v;
  h_fast[i] = 0x0000FFFE0000FFFEull;  // parity 0: non-matching tag
  h_safe[i] = 0x0000FFFE0000FFFEull;
}

// ---------------------------------------------------------------------------
// K1: xproj[b,t,:] = inp[b,t,:] @ W_ih  -> rnn slab (overwritten by h later)
// ---------------------------------------------------------------------------
__global__ __launch_bounds__(256) void xproj_kernel(
    const float* __restrict__ inp, const float* __restrict__ W_ih,
    float* __restrict__ rnn) {
  __shared__ float xin[16 * INP];
  const int tid = threadIdx.x;
  const long r0 = (long)blockIdx.x * 16;

  const float4* inp4 = (const float4*)(inp + r0 * INP);
  ((float4*)xin)[tid] = inp4[tid];
  __syncthreads();

  const int j = tid, j2 = tid + 256;
  float acc0[16], acc1[16];
#pragma unroll
  for (int r = 0; r < 16; ++r) { acc0[r] = 0.f; acc1[r] = 0.f; }

  for (int i = 0; i < INP; ++i) {
    const float w0 = W_ih[i * HID + j];
    const float w1 = W_ih[i * HID + j2];
#pragma unroll
    for (int r = 0; r < 16; ++r) {
      const float x = xin[r * INP + i];
      acc0[r] = fmaf(x, w0, acc0[r]);
      acc1[r] = fmaf(x, w1, acc1[r]);
    }
  }
#pragma unroll
  for (int r = 0; r < 16; ++r) {
    rnn[(r0 + r) * HID + j]  = acc0[r];
    rnn[(r0 + r) * HID + j2] = acc1[r];
  }
}

// ---------------------------------------------------------------------------
// K2: recurrence. W_hh register-resident bf16 B-frags. Claim-based same-XCD
// grouping; fence-free tagged-word exchange through the shared per-XCD L2,
// with globally-consistent fallback to the MALL path if claiming fails.
// ---------------------------------------------------------------------------
__global__ __launch_bounds__(512) void rnn_mfma(
    const float* __restrict__ W_hh, float* __restrict__ rnn,
    float* __restrict__ hn_out, uint64_t* __restrict__ h_fast,
    uint64_t* __restrict__ h_safe, uint32_t* __restrict__ ctrl) {
  __shared__ __align__(16) unsigned short hl[2][MROWS][HLPAD];
  __shared__ int sh_g, sh_s, sh_work, sh_mode;

  const int tid  = threadIdx.x;

  // ---- claim a (group, slice) slot on this block's physical XCD
  if (tid == 0) {
    uint32_t* cnt      = ctrl;          // [8]
    uint32_t* claimed  = ctrl + 8;
    uint32_t* arrivals = ctrl + 9;
    uint32_t* flag     = ctrl + 10;
    const int xcc = get_xcc_id();
    const int slot = (int)__hip_atomic_fetch_add(
        &cnt[xcc], 1u, __ATOMIC_RELAXED, __HIP_MEMORY_SCOPE_AGENT);
    int work = 0, g = 0, s = 0;
    if (slot < WORK_PER_XCD) {          // groups [4*xcc, 4*xcc+4) x 4 slices
      g = xcc * 4 + (slot >> 2);
      s = slot & 3;
      work = 1;
      __hip_atomic_fetch_add(claimed, 1u, __ATOMIC_RELEASE,
                             __HIP_MEMORY_SCOPE_AGENT);
    }
    const int arr = (int)__hip_atomic_fetch_add(
        arrivals, 1u, __ATOMIC_ACQ_REL, __HIP_MEMORY_SCOPE_AGENT);
    if (arr == NLAUNCH - 1) {           // last arriver decides, once, for all
      const uint32_t c = __hip_atomic_load(claimed, __ATOMIC_ACQUIRE,
                                           __HIP_MEMORY_SCOPE_AGENT);
      __hip_atomic_store(flag, (c == NBLOCKS) ? 2u : 1u, __ATOMIC_RELEASE,
                         __HIP_MEMORY_SCOPE_AGENT);
    }
    uint32_t f = 0; int guard = 0;
    do {
      f = __hip_atomic_load(flag, __ATOMIC_ACQUIRE, __HIP_MEMORY_SCOPE_AGENT);
    } while (f == 0 && ++guard < (1 << 20));
    if (f != 2) {                       // globally-consistent fallback layout
      work = (blockIdx.x < NBLOCKS);
      g = blockIdx.x & (NGROUP - 1);
      s = blockIdx.x >> 5;
    }
    sh_g = g; sh_s = s; sh_work = work; sh_mode = (f == 2);
  }
  __syncthreads();
  if (!sh_work) return;                 // block-uniform: no further barriers

  const int g = __builtin_amdgcn_readfirstlane(sh_g);
  const int s = __builtin_amdgcn_readfirstlane(sh_s);
  int fastmode = __builtin_amdgcn_readfirstlane(sh_mode);  // sticky

  const int lane = tid & 63;
  const int w    = tid >> 6;              // wave 0..7
  const int r0   = g * MROWS;
  const int n_base = s * COLS + w * 16;

  const int lm = lane & 15;               // MFMA m/n lane index
  const int lq = lane >> 4;               // quad 0..3 -> k-subchunk
  const int cc = n_base + lm;             // this lane's output column

  // ---- one-time: W_hh column slice -> bf16 B-frags
  // lane holds B[k = kt*32 + lq*8 + i][n = lm]
  short8 bfrag[16];
#pragma unroll
  for (int kt = 0; kt < 16; ++kt) {
    short8 f;
#pragma unroll
    for (int i = 0; i < 8; ++i) {
      const int k = kt * 32 + lq * 8 + i;
      __hip_bfloat16 hb = __float2bfloat16(W_hh[k * HID + cc]);
      f[i] = *reinterpret_cast<short*>(&hb);
    }
    bfrag[kt] = f;
  }

  const int  arow   = lm & 1;             // A row duplication (M=2 real rows)
  const bool remote = ((tid >> 7) != s);  // wave-uniform: outside own slice?
  const bool prod   = (lq == 0);          // producer lanes (hold C rows 0,1)

  // xp double-buffer: producer lanes only
  long ro0 = ((long)r0 * T + 0) * HID + cc;
  long ro1 = ((long)(r0 + 1) * T + 0) * HID + cc;
  float xp0 = 0.f, xp1 = 0.f;
  if (prod) { xp0 = rnn[ro0]; xp1 = rnn[ro1]; }

  for (int t = 0; t < T; ++t) {
    const int p = (t + 1) & 1;            // parity holding h_{t-1}

    // ---- poll tagged words (remote cols; everything at t==0)
    if (t == 0 || remote) {
      const size_t idx = ((size_t)p * NGROUP + g) * HID + tid;
      const uint64_t want = (uint64_t)(t & 0xFFFF) * 0x0000000100000001ull;
      uint64_t v = 0;
      if (fastmode) {
        int ok = 0;
        for (int it = 0; it < FAST_GUARD; ++it) {
          v = l2_load64(h_fast + idx);
          if (((v ^ want) & 0x0000FFFF0000FFFFull) == 0) { ok = 1; break; }
        }
        if (!ok) fastmode = 0;            // visibility failed: go MALL path
      }
      if (!fastmode) {                    // guaranteed path via MALL
        int guard = 0;
        for (;;) {
          v = __hip_atomic_load(h_safe + idx, __ATOMIC_RELAXED,
                                __HIP_MEMORY_SCOPE_AGENT);
          if (((v ^ want) & 0x0000FFFF0000FFFFull) == 0) break;
          if (++guard > (1 << 20)) break; // never hang the harness
        }
      }
      hl[p][0][tid] = (unsigned short)((uint32_t)v >> 16);
      hl[p][1][tid] = (unsigned short)((uint32_t)(v >> 32) >> 16);
    }
    __syncthreads();                      // one barrier/step (parity dbuf)

    // prefetch next step's xproj (hidden under MFMA + next poll)
    float nxp0 = 0.f, nxp1 = 0.f;
    long nro0 = ro0, nro1 = ro1;
    if (prod && t + 1 < T) {
      nro0 = ro0 + HID; nro1 = ro1 + HID;
      nxp0 = rnn[nro0]; nxp1 = rnn[nro1];
    }

    // ---- 16 MFMA over k, 4 independent chains (depth 4)
    floatx4 c0 = {0.f, 0.f, 0.f, 0.f}, c1 = c0, c2 = c0, c3 = c0;
    const unsigned short* ap = &hl[p][arow][lq * 8];
#pragma unroll
    for (int kt = 0; kt < 16; kt += 4) {
      short8 a0 = *(const short8*)(ap + (kt + 0) * 32);
      short8 a1 = *(const short8*)(ap + (kt + 1) * 32);
      short8 a2 = *(const short8*)(ap + (kt + 2) * 32);
      short8 a3 = *(const short8*)(ap + (kt + 3) * 32);
      c0 = __builtin_amdgcn_mfma_f32_16x16x32_bf16(a0, bfrag[kt + 0], c0, 0, 0, 0);
      c1 = __builtin_amdgcn_mfma_f32_16x16x32_bf16(a1, bfrag[kt + 1], c1, 0, 0, 0);
      c2 = __builtin_amdgcn_mfma_f32_16x16x32_bf16(a2, bfrag[kt + 2], c2, 0, 0, 0);
      c3 = __builtin_amdgcn_mfma_f32_16x16x32_bf16(a3, bfrag[kt + 3], c3, 0, 0, 0);
    }

    if (prod) {  // C layout: col = lane&15, row = (lane>>4)*4 + reg
      const float z0 = c0[0] + c1[0] + c2[0] + c3[0] + xp0;
      const float z1 = c0[1] + c1[1] + c2[1] + c3[1] + xp1;
      const float h0 = 1.f / (1.f + __expf(-z0));
      const float h1 = 1.f / (1.f + __expf(-z1));
      __hip_bfloat16 b0 = __float2bfloat16(h0);
      __hip_bfloat16 b1 = __float2bfloat16(h1);
      const unsigned short u0 = *reinterpret_cast<unsigned short*>(&b0);
      const unsigned short u1 = *reinterpret_cast<unsigned short*>(&b1);

      // critical path first: tagged word for remote consumers
      const uint32_t tag = (uint32_t)(t + 1) & 0xFFFFu;
      const uint64_t word =
          (uint64_t)(((uint32_t)u0 << 16) | tag) |
          ((uint64_t)(((uint32_t)u1 << 16) | tag) << 32);
      const size_t didx = ((size_t)(t & 1) * NGROUP + g) * HID + cc;
      l2_store64(h_fast + didx, word);    // same-XCD L2 (fast consumers)
      __hip_atomic_store(h_safe + didx, word, __ATOMIC_RELAXED,
                         __HIP_MEMORY_SCOPE_AGENT);  // MALL (fallback path)

      // own-slice bypass: stage h_t for our own next step directly in LDS
      hl[t & 1][0][cc] = u0;
      hl[t & 1][1][cc] = u1;

      // non-critical: f32 outputs
      rnn[ro0] = h0;
      rnn[ro1] = h1;
      if (t == T - 1) {
        hn_out[r0 * HID + cc]       = h0;
        hn_out[(r0 + 1) * HID + cc] = h1;
      }
      xp0 = nxp0; xp1 = nxp1; ro0 = nro0; ro1 = nro1;
    }
  }
}

// ---------------------------------------------------------------------------
// K3: out[b,t,:] = sigmoid(rnn[b,t,:] @ W_fc + b_fc)
// ---------------------------------------------------------------------------
__global__ __launch_bounds__(256) void fc_kernel(
    const float* __restrict__ rnn, const float* __restrict__ W_fc,
    const float* __restrict__ b_fc, float* __restrict__ out) {
  const int lane = threadIdx.x & 63;
  const int wid  = threadIdx.x >> 6;
  const long row = (long)blockIdx.x * 4 + wid;

  const float4* __restrict__ hrow = (const float4*)(rnn + row * HID);
  const float4* __restrict__ Wfc4 = (const float4*)W_fc;

  float a0 = 0.f, a1 = 0.f;
#pragma unroll
  for (int u = 0; u < 2; ++u) {
    const float4 hv = hrow[lane * 2 + u];
    const int j0 = lane * 8 + u * 4;
    const float4 wA = Wfc4[(j0 >> 1)];
    const float4 wB = Wfc4[(j0 >> 1) + 1];
    a0 += hv.x * wA.x + hv.y * wA.z + hv.z * wB.x + hv.w * wB.z;
    a1 += hv.x * wA.y + hv.y * wA.w + hv.z * wB.y + hv.w * wB.w;
  }
#pragma unroll
  for (int off = 32; off > 0; off >>= 1) {
    a0 += __shfl_down(a0, off, 64);
    a1 += __shfl_down(a1, off, 64);
  }
  if (lane == 0) {
    out[row * 2 + 0] = 1.f / (1.f + __expf(-(a0 + b_fc[0])));
    out[row * 2 + 1] = 1.f / (1.f + __expf(-(a1 + b_fc[1])));
  }
}

// ---------------------------------------------------------------------------
extern "C" void kernel_launch(void* const* d_in, const int* in_sizes, int n_in,
                              void* d_out, int out_size, void* d_ws,
                              size_t ws_size, hipStream_t stream) {
  const float* inp  = (const float*)d_in[0];
  const float* hn   = (const float*)d_in[1];
  const float* W_hh = (const float*)d_in[2];
  const float* W_ih = (const float*)d_in[3];
  const float* W_fc = (const float*)d_in[4];
  const float* b_fc = (const float*)d_in[5];

  float* out    = (float*)d_out;              // [B,T,ACT]
  float* hn_out = out + (long)B * T * ACT;    // [1,B,HID]
  float* rnn    = hn_out + (long)B * HID;     // [B,T,HID]

  // workspace: ctrl (256 B) | h_fast[2][NGROUP][HID] u64 (256 KB) | h_safe
  uint32_t* ctrl   = (uint32_t*)d_ws;
  uint64_t* h_fast = (uint64_t*)((char*)d_ws + 256);
  const size_t HCNT = (size_t)2 * NGROUP * HID;             // u64 words
  uint64_t* h_safe =
      (ws_size >= 256 + 2 * HCNT * sizeof(uint64_t)) ? (h_fast + HCNT)
                                                     : h_fast;  // alias-safe

  hipLaunchKernelGGL(init_kernel, dim3((NGROUP * HID) / 256), dim3(256), 0,
                     stream, hn, h_fast, h_safe, ctrl);
  hipLaunchKernelGGL(xproj_kernel, dim3((B * T) / 16), dim3(256), 0, stream,
                     inp, W_ih, rnn);
  hipLaunchKernelGGL(rnn_mfma, dim3(NLAUNCH), dim3(512), 0, stream,
                     W_hh, rnn, hn_out, h_fast, h_safe, ctrl);
  hipLaunchKernelGGL(fc_kernel, dim3((B * T) / 4), dim3(256), 0, stream,
                     rnn, W_fc, b_fc, out);
}